// Round 2
// baseline (1184.443 us; speedup 1.0000x reference)
//
#include <hip/hip_runtime.h>

#define NPTS 131072
#define DIM  128
#define KC   1024

// ws layout (floats): [0..1023] = 0.5*||e_k||^2 ; [1024..1535] = per-block loss partial sums

__global__ void vq_ee(const float* __restrict__ emb, float* __restrict__ ee) {
    // one wave per code: 1024 waves total
    int gid  = blockIdx.x * blockDim.x + threadIdx.x;
    int w    = gid >> 6;          // code id
    int lane = threadIdx.x & 63;
    const float* e = emb + (size_t)w * DIM;
    float a = e[lane];
    float b = e[lane + 64];
    float v = a * a + b * b;
    #pragma unroll
    for (int o = 32; o > 0; o >>= 1) v += __shfl_down(v, o);
    if (lane == 0) ee[w] = 0.5f * v;
}

__global__ __launch_bounds__(256, 1) void vq_main(const float* __restrict__ x,
                                                  const float* __restrict__ emb,
                                                  const float* __restrict__ ee,
                                                  float* __restrict__ out,
                                                  float* __restrict__ bsum) {
    const int p = blockIdx.x * 256 + threadIdx.x;

    // Load this point's row into registers (32 x float4 = 128 VGPRs)
    float4 xr[32];
    const float4* xv = reinterpret_cast<const float4*>(x + (size_t)p * DIM);
    #pragma unroll
    for (int i = 0; i < 32; ++i) xr[i] = xv[i];

    float best = -3.4e38f;
    int   bi   = 0;

    for (int k = 0; k < KC; ++k) {
        // force uniformity so codebook row streams through the scalar pipe
        const int ku = __builtin_amdgcn_readfirstlane(k);
        const float4* e4 = reinterpret_cast<const float4*>(emb + (size_t)ku * DIM);
        float a0 = 0.f, a1 = 0.f, a2 = 0.f, a3 = 0.f;
        #pragma unroll
        for (int i = 0; i < 32; ++i) {
            float4 ev = e4[i];
            a0 = fmaf(xr[i].x, ev.x, a0);
            a1 = fmaf(xr[i].y, ev.y, a1);
            a2 = fmaf(xr[i].z, ev.z, a2);
            a3 = fmaf(xr[i].w, ev.w, a3);
        }
        float s = ((a0 + a1) + (a2 + a3)) - ee[ku];   // = x.e - 0.5||e||^2
        if (s > best) { best = s; bi = k; }           // strict >: first max wins (matches argmin)
    }

    // index output (as float, per harness float32 readback)
    out[p] = (float)bi;

    // gather nearest code, write quantized_st (== quantized forward), accumulate loss
    const float4* q4 = reinterpret_cast<const float4*>(emb + (size_t)bi * DIM);
    float4* oq = reinterpret_cast<float4*>(out + (size_t)NPTS + (size_t)p * DIM);
    float lsum = 0.f;
    #pragma unroll
    for (int i = 0; i < 32; ++i) {
        float4 qv = q4[i];
        oq[i] = qv;
        float dx = qv.x - xr[i].x;
        float dy = qv.y - xr[i].y;
        float dz = qv.z - xr[i].z;
        float dw = qv.w - xr[i].w;
        lsum += dx * dx + dy * dy + dz * dz + dw * dw;
    }

    // deterministic block reduction of loss partial
    __shared__ float red[4];
    #pragma unroll
    for (int o = 32; o > 0; o >>= 1) lsum += __shfl_down(lsum, o);
    int lane = threadIdx.x & 63, wv = threadIdx.x >> 6;
    if (lane == 0) red[wv] = lsum;
    __syncthreads();
    if (threadIdx.x == 0) bsum[blockIdx.x] = (red[0] + red[1]) + (red[2] + red[3]);
}

__global__ void vq_finalize(const float* __restrict__ bsum, float* __restrict__ out) {
    __shared__ float red[8];
    int t = threadIdx.x;  // 512 threads
    float v = bsum[t];
    #pragma unroll
    for (int o = 32; o > 0; o >>= 1) v += __shfl_down(v, o);
    if ((t & 63) == 0) red[t >> 6] = v;
    __syncthreads();
    if (t == 0) {
        float s = 0.f;
        #pragma unroll
        for (int i = 0; i < 8; ++i) s += red[i];
        // vq_loss = beta*mean + mean = 1.25 * sum / (N*D)
        out[(size_t)NPTS + (size_t)NPTS * DIM] = 1.25f * s / 16777216.0f;
    }
}

extern "C" void kernel_launch(void* const* d_in, const int* in_sizes, int n_in,
                              void* d_out, int out_size, void* d_ws, size_t ws_size,
                              hipStream_t stream) {
    const float* x   = (const float*)d_in[0];
    const float* emb = (const float*)d_in[1];
    float* out  = (float*)d_out;
    float* ws   = (float*)d_ws;
    float* ee   = ws;          // 1024 floats
    float* bsum = ws + 1024;   // 512 floats

    vq_ee<<<256, 256, 0, stream>>>(emb, ee);                 // 1024 waves, one per code
    vq_main<<<512, 256, 0, stream>>>(x, emb, ee, out, bsum); // 1 thread per point
    vq_finalize<<<1, 512, 0, stream>>>(bsum, out);
}